// Round 2
// baseline (67.649 us; speedup 1.0000x reference)
//
#include <hip/hip_runtime.h>

// OneHotEmbedding == row gather: out[i,:] = embeddings[inputs[i],:]
// N=16384, VOCAB=32000, EMB=128 (float32).
//
// v2b: ILP-2 same-row + nontemporal stores (fixed: native vector type for
// __builtin_nontemporal_store — HIP_vector_type<float,4> is a struct and
// is rejected by the builtin; ext_vector_type(4) is accepted).
//  - 16 threads per row; each thread handles float4 columns c and c+16.
//    -> ONE idx load feeds TWO independent table loads (2x outstanding
//       loads per wave vs v1's single dependent chain), idx traffic halved.
//  - Nontemporal stores: output is written once and never re-read; keep it
//    out of the 4 MiB/XCD L2 so gathered table lines (16.4 MB total) stay.
//  - 32-bit offset arithmetic: e*32 + c <= 32000*32, fits easily.
// Coalescing: per 16-lane group each load/store instruction touches a
// contiguous 256 B segment -> fully coalesced.

#define N_ROWS 16384
#define EMB 128
#define EMB4 (EMB / 4)   // 32 float4 per row
#define HALF (EMB4 / 2)  // 16 float4; threads per row

typedef float f4 __attribute__((ext_vector_type(4)));

__global__ __launch_bounds__(256) void OneHotEmbedding_87522843561070_kernel(
    const int* __restrict__ idx,
    const f4* __restrict__ emb,
    f4* __restrict__ out) {
    int t = blockIdx.x * blockDim.x + threadIdx.x;  // 0 .. N_ROWS*HALF-1
    int row = t >> 4;       // 16 threads per row
    int c   = t & 15;       // float4 column 0..15 (pair partner is c+16)

    int e = idx[row];

    int ebase = e * EMB4 + c;      // 32-bit, max ~1.02M float4 units
    f4 v0 = emb[ebase];
    f4 v1 = emb[ebase + HALF];

    int obase = row * EMB4 + c;
    __builtin_nontemporal_store(v0, &out[obase]);
    __builtin_nontemporal_store(v1, &out[obase + HALF]);
}

extern "C" void kernel_launch(void* const* d_in, const int* in_sizes, int n_in,
                              void* d_out, int out_size, void* d_ws, size_t ws_size,
                              hipStream_t stream) {
    const int* idx = (const int*)d_in[0];
    const f4* emb = (const f4*)d_in[1];
    f4* out = (f4*)d_out;

    const int total = N_ROWS * HALF;   // 262144 threads
    const int block = 256;
    const int grid = total / block;    // 1024 blocks -> 4 blocks/CU, 16 waves/CU

    OneHotEmbedding_87522843561070_kernel<<<grid, block, 0, stream>>>(idx, emb, out);
}